// Round 2
// baseline (868.731 us; speedup 1.0000x reference)
//
#include <hip/hip_runtime.h>
#include <stdint.h>

typedef __attribute__((ext_vector_type(8))) short bf16x8;   // 8 bf16 = 4 VGPRs
typedef __attribute__((ext_vector_type(4))) float f32x4;

__device__ __forceinline__ float bf2f(unsigned short b) {
    union { unsigned u; float f; } c; c.u = ((unsigned)b) << 16; return c.f;
}
__device__ __forceinline__ unsigned short f2bf(float f) {
    union { float f; unsigned u; } c; c.f = f;
    unsigned u = c.u;
    u += 0x7fffu + ((u >> 16) & 1u);          // round-to-nearest-even
    return (unsigned short)(u >> 16);
}

__global__ void GNNEncoder_317827579954_kernel() {}

__global__ void k_zero(int* __restrict__ p, int n) {
    int i = blockIdx.x * 256 + threadIdx.x;
    if (i < n) p[i] = 0;
}

// flags[0] = 1 if dense inputs are f32 (else bf16); flags[1] = 1 if edge_index is int64.
__global__ void k_flags(const unsigned* __restrict__ x, const int* __restrict__ ei,
                        int E, int* __restrict__ flags) {
    int t = threadIdx.x;              // 0..63
    int pl = 0;
    for (int i = t; i < 256; i += 64) {
        unsigned u = x[i] & 0xffffu;
        unsigned e = (u >> 7) & 0xffu;
        if ((e >= 100u && e <= 145u) || u == 0u) ++pl;
    }
    for (int off = 32; off; off >>= 1) pl += __shfl_down(pl, off);
    int n = E < 64 ? E : 64;
    unsigned long long nz = __ballot(t < n ? (ei[2 * t + 1] != 0) : 0);
    if (t == 0) {
        flags[0] = (pl >= 192) ? 0 : 1;       // 0 = bf16, 1 = f32
        flags[1] = (nz == 0ull) ? 1 : 0;      // 1 = int64
    }
}

// Normalize x into bf16, 8 elements/thread.
__global__ void k_cvt8(const void* __restrict__ in, unsigned short* __restrict__ out,
                       int n8, const int* __restrict__ flags) {
    int i = blockIdx.x * 256 + threadIdx.x;
    if (i >= n8) return;
    if (flags[0]) {
        const float4* f = (const float4*)in;
        float4 x0 = f[i * 2], x1 = f[i * 2 + 1];
        union { unsigned short s[8]; uint4 v; } o;
        o.s[0] = f2bf(x0.x); o.s[1] = f2bf(x0.y); o.s[2] = f2bf(x0.z); o.s[3] = f2bf(x0.w);
        o.s[4] = f2bf(x1.x); o.s[5] = f2bf(x1.y); o.s[6] = f2bf(x1.z); o.s[7] = f2bf(x1.w);
        ((uint4*)out)[i] = o.v;
    } else {
        ((uint4*)out)[i] = ((const uint4*)in)[i];
    }
}

// W [k][n] (raw dtype) -> Wt [n][k] bf16 (256x256)
__global__ void k_cvtT(const void* __restrict__ W, unsigned short* __restrict__ Wt,
                       const int* __restrict__ flags) {
    int n = blockIdx.x, k = threadIdx.x;
    unsigned short v;
    if (flags[0]) v = f2bf(((const float*)W)[k * 256 + n]);
    else          v = ((const unsigned short*)W)[k * 256 + n];
    Wt[n * 256 + k] = v;
}

// ---- two-level counting-sort CSR build ----
// Buckets of 64 nodes: bucket b covers dst in [b*64, b*64+64). NB = ceil(N/64) <= 1024.

// Bucket histogram with per-block LDS aggregation (grid-stride).
__global__ __launch_bounds__(256) void k_bcount(const int* __restrict__ ei, int E,
                                                const int* __restrict__ flags,
                                                int* __restrict__ bcnt, int nb) {
    __shared__ int lc[1024];
    int t = threadIdx.x;
    for (int i = t; i < nb; i += 256) lc[i] = 0;
    __syncthreads();
    int i64 = flags[1];
    int stride = gridDim.x * 256;
    for (int i = blockIdx.x * 256 + t; i < E; i += stride) {
        int d = i64 ? ei[2 * E + 2 * i] : ei[E + i];
        atomicAdd(&lc[d >> 6], 1);
    }
    __syncthreads();
    for (int i = t; i < nb; i += 256) {
        int v = lc[i];
        if (v) atomicAdd(&bcnt[i], v);
    }
}

// One-block exclusive scan over nb (<=1024) bucket counts.
__global__ __launch_bounds__(1024) void k_bscan(const int* __restrict__ bcnt,
                                                int* __restrict__ boff,
                                                int* __restrict__ bcur,
                                                int* __restrict__ offs,
                                                int nb, int N, int E) {
    __shared__ int sc[1024];
    int t = threadIdx.x;
    int v = (t < nb) ? bcnt[t] : 0;
    sc[t] = v;
    __syncthreads();
    for (int off = 1; off < 1024; off <<= 1) {
        int u = (t >= off) ? sc[t - off] : 0;
        __syncthreads();
        sc[t] += u;
        __syncthreads();
    }
    if (t < nb) {
        int ex = sc[t] - v;
        boff[t] = ex;
        bcur[t] = ex;
    }
    if (t == 0) { boff[nb] = E; offs[N] = E; }
}

// Scatter edges into bucket-ordered tmp; packed word = (src<<6) | (dst & 63).
// Writes within a bucket region are grabbed in adjacent slots -> lines fill in L2.
__global__ __launch_bounds__(256) void k_scatter(const int* __restrict__ ei, int E,
                                                 const int* __restrict__ flags,
                                                 int* __restrict__ bcur,
                                                 unsigned* __restrict__ tmp) {
    int i = blockIdx.x * 256 + threadIdx.x;
    if (i >= E) return;
    int s, d;
    if (flags[1]) { s = ei[2 * i]; d = ei[2 * E + 2 * i]; }
    else          { s = ei[i];     d = ei[E + i]; }
    int p = atomicAdd(&bcur[d >> 6], 1);
    tmp[p] = ((unsigned)s << 6) | (unsigned)(d & 63);
}

// Per-bucket: LDS degree count + scan (-> offs, dinv), then in-bucket CSR fill.
// Bucket CSR region (~8 KB avg) is L2-resident during the scatter.
__global__ __launch_bounds__(256) void k_bbuild(const unsigned* __restrict__ tmp,
                                                const int* __restrict__ boff,
                                                int* __restrict__ offs,
                                                float* __restrict__ dinv,
                                                int* __restrict__ csr, int N) {
    __shared__ int ldeg[64], lex[64], lcur[64];
    int b = blockIdx.x;
    int t = threadIdx.x;
    int base = b * 64;
    int beg = boff[b], end = boff[b + 1];
    if (t < 64) ldeg[t] = 0;
    __syncthreads();
    for (int i = beg + t; i < end; i += 256) {
        unsigned u = tmp[i];
        atomicAdd(&ldeg[u & 63u], 1);
    }
    __syncthreads();
    if (t == 0) {
        int run = 0;
        for (int i = 0; i < 64; ++i) {
            int v = ldeg[i];
            lex[i] = run; lcur[i] = run;
            run += v;
        }
    }
    __syncthreads();
    if (t < 64) {
        int v = base + t;
        if (v < N) {
            offs[v] = beg + lex[t];
            dinv[v] = rsqrtf((float)(ldeg[t] + 1));   // +1 = self loop
        }
    }
    for (int i = beg + t; i < end; i += 256) {
        unsigned u = tmp[i];
        int p = atomicAdd(&lcur[u & 63u], 1);
        csr[beg + p] = (int)(u >> 6);
    }
}

// C[M,256] = A[M,256] @ Bt^T. 1D grid; wave computes 16 rows x 256 cols.
__global__ __launch_bounds__(256) void k_gemm(const unsigned short* __restrict__ A,
                                              const unsigned short* __restrict__ Bt,
                                              unsigned short* __restrict__ C, int M) {
    int tid  = threadIdx.x;
    int lane = tid & 63;
    int wave = tid >> 6;
    int q = lane >> 4;
    int r = lane & 15;
    int rowBase = blockIdx.x * 64 + wave * 16;

    int arow = rowBase + r;
    arow = arow < M ? arow : M - 1;
    const unsigned short* aptr = A + (size_t)arow * 256;

    f32x4 acc[16] = {};
    for (int kk = 0; kk < 256; kk += 32) {
        int k = kk + q * 8;
        bf16x8 a = *(const bf16x8*)(aptr + k);
#pragma unroll
        for (int nt = 0; nt < 16; ++nt) {
            bf16x8 b = *(const bf16x8*)(Bt + (size_t)(nt * 16 + r) * 256 + k);
            acc[nt] = __builtin_amdgcn_mfma_f32_16x16x32_bf16(a, b, acc[nt], 0, 0, 0);
        }
    }
#pragma unroll
    for (int nt = 0; nt < 16; ++nt) {
        int col = nt * 16 + r;
#pragma unroll
        for (int r2 = 0; r2 < 4; ++r2) {
            int row = rowBase + q * 4 + r2;
            if (row < M) C[(size_t)row * 256 + col] = f2bf(acc[nt][r2]);
        }
    }
}

// Full-row gather aggregation with 8x edge unroll for memory-level parallelism.
// One wave per node; lane owns 4 channels (uint2 = 8 B); 64 lanes = full 512-B row.
__global__ __launch_bounds__(256) void k_agg(const unsigned short* __restrict__ XW,
                                             const int* __restrict__ csr,
                                             const int* __restrict__ offs,
                                             const float* __restrict__ dinv,
                                             const void* __restrict__ bias,
                                             void* __restrict__ out,
                                             int relu, int final_, const int* __restrict__ flags,
                                             int N) {
    int v = blockIdx.x * 4 + (threadIdx.x >> 6);
    if (v >= N) return;
    int lane = threadIdx.x & 63;
    int c = lane * 4;
    float a0 = 0.f, a1 = 0.f, a2 = 0.f, a3 = 0.f;
    int beg = offs[v], end = offs[v + 1];
    int e = beg;
    for (; e + 8 <= end; e += 8) {
        int s[8]; float w[8]; uint2 u[8];
#pragma unroll
        for (int j = 0; j < 8; ++j) s[j] = csr[e + j];
#pragma unroll
        for (int j = 0; j < 8; ++j) w[j] = dinv[s[j]];
#pragma unroll
        for (int j = 0; j < 8; ++j) u[j] = *(const uint2*)(XW + (size_t)s[j] * 256 + c);
#pragma unroll
        for (int j = 0; j < 8; ++j) {
            a0 += w[j] * bf2f((unsigned short)(u[j].x & 0xffffu));
            a1 += w[j] * bf2f((unsigned short)(u[j].x >> 16));
            a2 += w[j] * bf2f((unsigned short)(u[j].y & 0xffffu));
            a3 += w[j] * bf2f((unsigned short)(u[j].y >> 16));
        }
    }
    for (; e < end; ++e) {
        int s = csr[e];
        float w = dinv[s];
        uint2 u = *(const uint2*)(XW + (size_t)s * 256 + c);
        a0 += w * bf2f((unsigned short)(u.x & 0xffffu));
        a1 += w * bf2f((unsigned short)(u.x >> 16));
        a2 += w * bf2f((unsigned short)(u.y & 0xffffu));
        a3 += w * bf2f((unsigned short)(u.y >> 16));
    }
    float dv = dinv[v];
    float dv2 = dv * dv;
    uint2 su = *(const uint2*)(XW + (size_t)v * 256 + c);
    float b0, b1, b2, b3;
    if (flags[0]) {
        const float* bf = (const float*)bias;
        b0 = bf[c]; b1 = bf[c + 1]; b2 = bf[c + 2]; b3 = bf[c + 3];
    } else {
        const unsigned short* bb = (const unsigned short*)bias;
        b0 = bf2f(bb[c]); b1 = bf2f(bb[c + 1]); b2 = bf2f(bb[c + 2]); b3 = bf2f(bb[c + 3]);
    }
    float r0 = dv * a0 + dv2 * bf2f((unsigned short)(su.x & 0xffffu)) + b0;
    float r1 = dv * a1 + dv2 * bf2f((unsigned short)(su.x >> 16))     + b1;
    float r2 = dv * a2 + dv2 * bf2f((unsigned short)(su.y & 0xffffu)) + b2;
    float r3 = dv * a3 + dv2 * bf2f((unsigned short)(su.y >> 16))     + b3;
    if (relu) {
        r0 = fmaxf(r0, 0.f); r1 = fmaxf(r1, 0.f);
        r2 = fmaxf(r2, 0.f); r3 = fmaxf(r3, 0.f);
    }
    if (final_ && flags[0]) {
        float4 o; o.x = r0; o.y = r1; o.z = r2; o.w = r3;
        *(float4*)((float*)out + (size_t)v * 256 + c) = o;
    } else {
        uint2 o;
        o.x = (unsigned)f2bf(r0) | ((unsigned)f2bf(r1) << 16);
        o.y = (unsigned)f2bf(r2) | ((unsigned)f2bf(r3) << 16);
        *(uint2*)((unsigned short*)out + (size_t)v * 256 + c) = o;
    }
}

extern "C" void kernel_launch(void* const* d_in, const int* in_sizes, int n_in,
                              void* d_out, int out_size, void* d_ws, size_t ws_size,
                              hipStream_t stream) {
    (void)n_in; (void)out_size; (void)ws_size;
    const void* x  = d_in[0];
    const int*  ei = (const int*)d_in[1];
    const void* W1 = d_in[2];
    const void* b1 = d_in[3];
    const void* W2 = d_in[4];
    const void* b2 = d_in[5];

    int N = in_sizes[0] / 256;          // 50000
    int E = in_sizes[1] / 2;            // 1600000
    int NB = (N + 63) / 64;             // 782 buckets of 64 nodes

    char* p = (char*)d_ws;
    auto alloc = [&](size_t bytes) {
        char* r = p;
        p += (bytes + 255) & ~(size_t)255;
        return r;
    };
    int*            flags  = (int*)alloc(8);
    int*            bcnt   = (int*)alloc(1024 * 4);
    int*            boff   = (int*)alloc(1028 * 4);
    int*            bcur   = (int*)alloc(1024 * 4);
    int*            offs   = (int*)alloc(((size_t)N + 1) * 4);
    float*          dinv   = (float*)alloc((size_t)N * 4);
    unsigned short* wt1    = (unsigned short*)alloc(256 * 256 * 2);
    unsigned short* wt2    = (unsigned short*)alloc(256 * 256 * 2);
    int*            csr    = (int*)alloc((size_t)E * 4);
    unsigned short* buf0   = (unsigned short*)alloc((size_t)N * 256 * 2);
    unsigned short* buf1   = (unsigned short*)alloc((size_t)N * 256 * 2);
    unsigned*       tmp    = (unsigned*)buf1;   // dead until first gemm; E*4 <= N*512

    int nF = N * 256;
    int gE = (E + 255) / 256;

    k_flags<<<1, 64, 0, stream>>>((const unsigned*)x, ei, E, flags);
    k_zero<<<(NB + 255) / 256, 256, 0, stream>>>(bcnt, NB);
    k_bcount<<<512, 256, 0, stream>>>(ei, E, flags, bcnt, NB);
    k_bscan<<<1, 1024, 0, stream>>>(bcnt, boff, bcur, offs, NB, N, E);
    k_scatter<<<gE, 256, 0, stream>>>(ei, E, flags, bcur, tmp);
    k_bbuild<<<NB, 256, 0, stream>>>(tmp, boff, offs, dinv, csr, N);

    k_cvt8<<<(nF / 8 + 255) / 256, 256, 0, stream>>>(x, buf0, nF / 8, flags);
    k_cvtT<<<256, 256, 0, stream>>>(W1, wt1, flags);
    k_cvtT<<<256, 256, 0, stream>>>(W2, wt2, flags);

    int gAgg = (N + 3) / 4;
    k_gemm<<<(N + 63) / 64, 256, 0, stream>>>(buf0, wt1, buf1, N);           // XW1
    k_agg<<<gAgg, 256, 0, stream>>>(buf1, csr, offs, dinv, b1,
                                    (void*)buf0, 1, 0, flags, N);            // h (bf16)
    k_gemm<<<(N + 63) / 64, 256, 0, stream>>>(buf0, wt2, buf1, N);           // HW2
    k_agg<<<gAgg, 256, 0, stream>>>(buf1, csr, offs, dinv, b2,
                                    d_out, 0, 1, flags, N);                  // final
}

// Round 3
// 561.276 us; speedup vs baseline: 1.5478x; 1.5478x over previous
//
#include <hip/hip_runtime.h>
#include <stdint.h>

typedef __attribute__((ext_vector_type(8))) short bf16x8;   // 8 bf16 = 4 VGPRs
typedef __attribute__((ext_vector_type(4))) float f32x4;

#define NBLK 256            // edge-chunk blocks for the deterministic counting sort
#define BSH  7              // bucket = 128 nodes
#define BSZ  128

__device__ __forceinline__ float bf2f(unsigned short b) {
    union { unsigned u; float f; } c; c.u = ((unsigned)b) << 16; return c.f;
}
__device__ __forceinline__ unsigned short f2bf(float f) {
    union { float f; unsigned u; } c; c.f = f;
    unsigned u = c.u;
    u += 0x7fffu + ((u >> 16) & 1u);          // round-to-nearest-even
    return (unsigned short)(u >> 16);
}

__global__ void GNNEncoder_317827579954_kernel() {}

// flags[0] = 1 if dense inputs are f32 (else bf16); flags[1] = 1 if edge_index is int64.
__global__ void k_flags(const unsigned* __restrict__ x, const int* __restrict__ ei,
                        int E, int* __restrict__ flags) {
    int t = threadIdx.x;              // 0..63
    int pl = 0;
    for (int i = t; i < 256; i += 64) {
        unsigned u = x[i] & 0xffffu;
        unsigned e = (u >> 7) & 0xffu;
        if ((e >= 100u && e <= 145u) || u == 0u) ++pl;
    }
    for (int off = 32; off; off >>= 1) pl += __shfl_down(pl, off);
    int n = E < 64 ? E : 64;
    unsigned long long nz = __ballot(t < n ? (ei[2 * t + 1] != 0) : 0);
    if (t == 0) {
        flags[0] = (pl >= 192) ? 0 : 1;       // 0 = bf16, 1 = f32
        flags[1] = (nz == 0ull) ? 1 : 0;      // 1 = int64
    }
}

// Normalize x into bf16, 8 elements/thread.
__global__ void k_cvt8(const void* __restrict__ in, unsigned short* __restrict__ out,
                       int n8, const int* __restrict__ flags) {
    int i = blockIdx.x * 256 + threadIdx.x;
    if (i >= n8) return;
    if (flags[0]) {
        const float4* f = (const float4*)in;
        float4 x0 = f[i * 2], x1 = f[i * 2 + 1];
        union { unsigned short s[8]; uint4 v; } o;
        o.s[0] = f2bf(x0.x); o.s[1] = f2bf(x0.y); o.s[2] = f2bf(x0.z); o.s[3] = f2bf(x0.w);
        o.s[4] = f2bf(x1.x); o.s[5] = f2bf(x1.y); o.s[6] = f2bf(x1.z); o.s[7] = f2bf(x1.w);
        ((uint4*)out)[i] = o.v;
    } else {
        ((uint4*)out)[i] = ((const uint4*)in)[i];
    }
}

// W [k][n] (raw dtype) -> Wt [n][k] bf16 (256x256)
__global__ void k_cvtT(const void* __restrict__ W, unsigned short* __restrict__ Wt,
                       const int* __restrict__ flags) {
    int n = blockIdx.x, k = threadIdx.x;
    unsigned short v;
    if (flags[0]) v = f2bf(((const float*)W)[k * 256 + n]);
    else          v = ((const unsigned short*)W)[k * 256 + n];
    Wt[n * 256 + k] = v;
}

// ---- deterministic two-level counting-sort CSR build (ZERO global atomics) ----
// Buckets of 128 nodes; nb = ceil(N/128) <= 512. NBLK edge-chunk blocks.
// cmat layout: [bucket][block]  (row of NBLK ints per bucket, contiguous).

// Per-block LDS histogram of its contiguous edge chunk -> cmat column.
__global__ __launch_bounds__(256) void k_cmat(const int* __restrict__ ei, int E,
                                              const int* __restrict__ flags,
                                              int* __restrict__ cmat, int nb) {
    __shared__ int lc[512];
    int t = threadIdx.x, b = blockIdx.x;
    for (int i = t; i < nb; i += 256) lc[i] = 0;
    __syncthreads();
    int chunk = (E + NBLK - 1) / NBLK;
    int beg = b * chunk;
    int end = beg + chunk; if (end > E) end = E;
    int i64 = flags[1];
    for (int i = beg + t; i < end; i += 256) {
        int d = i64 ? ei[2 * E + 2 * i] : ei[E + i];
        atomicAdd(&lc[d >> BSH], 1);
    }
    __syncthreads();
    for (int j = t; j < nb; j += 256) cmat[j * NBLK + b] = lc[j];
}

// One block: per-bucket exclusive prefix over blocks (in place), cross-bucket scan -> boff.
__global__ __launch_bounds__(512) void k_cscan(int* __restrict__ cmat,
                                               int* __restrict__ boff,
                                               int* __restrict__ offs,
                                               int nb, int N, int E) {
    __shared__ int sc[512];
    int t = threadIdx.x;
    int run = 0;
    if (t < nb) {
        int* row = cmat + t * NBLK;
        for (int b = 0; b < NBLK; ++b) { int v = row[b]; row[b] = run; run += v; }
    }
    sc[t] = run;                       // bucket total (0 for t >= nb)
    __syncthreads();
    int val = run;
    for (int off = 1; off < 512; off <<= 1) {
        int u = (t >= off) ? sc[t - off] : 0;
        __syncthreads();
        sc[t] += u;
        __syncthreads();
    }
    int ex = sc[t] - val;              // exclusive prefix of bucket totals
    if (t < nb) {
        boff[t] = ex;
        int* row = cmat + t * NBLK;
        for (int b = 0; b < NBLK; ++b) row[b] += ex;
    }
    if (t == 0) { boff[nb] = E; offs[N] = E; }
}

// Deterministic scatter: LDS cursors start at this block's reserved bases.
// Each block writes ~contiguous runs per bucket from ONE XCD -> lines fill in L2.
__global__ __launch_bounds__(256) void k_fillmat(const int* __restrict__ ei, int E,
                                                 const int* __restrict__ flags,
                                                 const int* __restrict__ cmat,
                                                 unsigned* __restrict__ tmp, int nb) {
    __shared__ int cur[512];
    int t = threadIdx.x, b = blockIdx.x;
    for (int j = t; j < nb; j += 256) cur[j] = cmat[j * NBLK + b];
    __syncthreads();
    int chunk = (E + NBLK - 1) / NBLK;
    int beg = b * chunk;
    int end = beg + chunk; if (end > E) end = E;
    int i64 = flags[1];
    for (int i = beg + t; i < end; i += 256) {
        int s, d;
        if (i64) { s = ei[2 * i]; d = ei[2 * E + 2 * i]; }
        else     { s = ei[i];     d = ei[E + i]; }
        int p = atomicAdd(&cur[d >> BSH], 1);        // LDS atomic only
        tmp[p] = ((unsigned)s << BSH) | (unsigned)(d & (BSZ - 1));
    }
}

// Per-bucket: LDS degree count + scan (-> offs, dinv), then in-bucket CSR fill.
// Bucket CSR region (~16 KB avg) is L2-resident during the fill.
__global__ __launch_bounds__(256) void k_bbuild(const unsigned* __restrict__ tmp,
                                                const int* __restrict__ boff,
                                                int* __restrict__ offs,
                                                float* __restrict__ dinv,
                                                int* __restrict__ csr, int N) {
    __shared__ int ldeg[BSZ], lex[BSZ], lcur[BSZ];
    int b = blockIdx.x;
    int t = threadIdx.x;
    int base = b << BSH;
    int beg = boff[b], end = boff[b + 1];
    if (t < BSZ) ldeg[t] = 0;
    __syncthreads();
    for (int i = beg + t; i < end; i += 256) {
        unsigned u = tmp[i];
        atomicAdd(&ldeg[u & (BSZ - 1u)], 1);
    }
    __syncthreads();
    if (t == 0) {
        int run = 0;
        for (int i = 0; i < BSZ; ++i) {
            int v = ldeg[i];
            lex[i] = run; lcur[i] = run;
            run += v;
        }
    }
    __syncthreads();
    if (t < BSZ) {
        int v = base + t;
        if (v < N) {
            offs[v] = beg + lex[t];
            dinv[v] = rsqrtf((float)(ldeg[t] + 1));   // +1 = self loop
        }
    }
    for (int i = beg + t; i < end; i += 256) {
        unsigned u = tmp[i];
        int p = atomicAdd(&lcur[u & (BSZ - 1u)], 1);
        csr[beg + p] = (int)(u >> BSH);
    }
}

// C[M,256] = A[M,256] @ Bt^T. 1D grid; wave computes 16 rows x 256 cols.
__global__ __launch_bounds__(256) void k_gemm(const unsigned short* __restrict__ A,
                                              const unsigned short* __restrict__ Bt,
                                              unsigned short* __restrict__ C, int M) {
    int tid  = threadIdx.x;
    int lane = tid & 63;
    int wave = tid >> 6;
    int q = lane >> 4;
    int r = lane & 15;
    int rowBase = blockIdx.x * 64 + wave * 16;

    int arow = rowBase + r;
    arow = arow < M ? arow : M - 1;
    const unsigned short* aptr = A + (size_t)arow * 256;

    f32x4 acc[16] = {};
    for (int kk = 0; kk < 256; kk += 32) {
        int k = kk + q * 8;
        bf16x8 a = *(const bf16x8*)(aptr + k);
#pragma unroll
        for (int nt = 0; nt < 16; ++nt) {
            bf16x8 b = *(const bf16x8*)(Bt + (size_t)(nt * 16 + r) * 256 + k);
            acc[nt] = __builtin_amdgcn_mfma_f32_16x16x32_bf16(a, b, acc[nt], 0, 0, 0);
        }
    }
#pragma unroll
    for (int nt = 0; nt < 16; ++nt) {
        int col = nt * 16 + r;
#pragma unroll
        for (int r2 = 0; r2 < 4; ++r2) {
            int row = rowBase + q * 4 + r2;
            if (row < M) C[(size_t)row * 256 + col] = f2bf(acc[nt][r2]);
        }
    }
}

// Full-row gather aggregation with 8x edge unroll for memory-level parallelism.
// One wave per node; lane owns 4 channels (uint2 = 8 B); 64 lanes = full 512-B row.
__global__ __launch_bounds__(256) void k_agg(const unsigned short* __restrict__ XW,
                                             const int* __restrict__ csr,
                                             const int* __restrict__ offs,
                                             const float* __restrict__ dinv,
                                             const void* __restrict__ bias,
                                             void* __restrict__ out,
                                             int relu, int final_, const int* __restrict__ flags,
                                             int N) {
    int v = blockIdx.x * 4 + (threadIdx.x >> 6);
    if (v >= N) return;
    int lane = threadIdx.x & 63;
    int c = lane * 4;
    float a0 = 0.f, a1 = 0.f, a2 = 0.f, a3 = 0.f;
    int beg = offs[v], end = offs[v + 1];
    int e = beg;
    for (; e + 8 <= end; e += 8) {
        int s[8]; float w[8]; uint2 u[8];
#pragma unroll
        for (int j = 0; j < 8; ++j) s[j] = csr[e + j];
#pragma unroll
        for (int j = 0; j < 8; ++j) w[j] = dinv[s[j]];
#pragma unroll
        for (int j = 0; j < 8; ++j) u[j] = *(const uint2*)(XW + (size_t)s[j] * 256 + c);
#pragma unroll
        for (int j = 0; j < 8; ++j) {
            a0 += w[j] * bf2f((unsigned short)(u[j].x & 0xffffu));
            a1 += w[j] * bf2f((unsigned short)(u[j].x >> 16));
            a2 += w[j] * bf2f((unsigned short)(u[j].y & 0xffffu));
            a3 += w[j] * bf2f((unsigned short)(u[j].y >> 16));
        }
    }
    for (; e < end; ++e) {
        int s = csr[e];
        float w = dinv[s];
        uint2 u = *(const uint2*)(XW + (size_t)s * 256 + c);
        a0 += w * bf2f((unsigned short)(u.x & 0xffffu));
        a1 += w * bf2f((unsigned short)(u.x >> 16));
        a2 += w * bf2f((unsigned short)(u.y & 0xffffu));
        a3 += w * bf2f((unsigned short)(u.y >> 16));
    }
    float dv = dinv[v];
    float dv2 = dv * dv;
    uint2 su = *(const uint2*)(XW + (size_t)v * 256 + c);
    float b0, b1, b2, b3;
    if (flags[0]) {
        const float* bf = (const float*)bias;
        b0 = bf[c]; b1 = bf[c + 1]; b2 = bf[c + 2]; b3 = bf[c + 3];
    } else {
        const unsigned short* bb = (const unsigned short*)bias;
        b0 = bf2f(bb[c]); b1 = bf2f(bb[c + 1]); b2 = bf2f(bb[c + 2]); b3 = bf2f(bb[c + 3]);
    }
    float r0 = dv * a0 + dv2 * bf2f((unsigned short)(su.x & 0xffffu)) + b0;
    float r1 = dv * a1 + dv2 * bf2f((unsigned short)(su.x >> 16))     + b1;
    float r2 = dv * a2 + dv2 * bf2f((unsigned short)(su.y & 0xffffu)) + b2;
    float r3 = dv * a3 + dv2 * bf2f((unsigned short)(su.y >> 16))     + b3;
    if (relu) {
        r0 = fmaxf(r0, 0.f); r1 = fmaxf(r1, 0.f);
        r2 = fmaxf(r2, 0.f); r3 = fmaxf(r3, 0.f);
    }
    if (final_ && flags[0]) {
        float4 o; o.x = r0; o.y = r1; o.z = r2; o.w = r3;
        *(float4*)((float*)out + (size_t)v * 256 + c) = o;
    } else {
        uint2 o;
        o.x = (unsigned)f2bf(r0) | ((unsigned)f2bf(r1) << 16);
        o.y = (unsigned)f2bf(r2) | ((unsigned)f2bf(r3) << 16);
        *(uint2*)((unsigned short*)out + (size_t)v * 256 + c) = o;
    }
}

extern "C" void kernel_launch(void* const* d_in, const int* in_sizes, int n_in,
                              void* d_out, int out_size, void* d_ws, size_t ws_size,
                              hipStream_t stream) {
    (void)n_in; (void)out_size; (void)ws_size;
    const void* x  = d_in[0];
    const int*  ei = (const int*)d_in[1];
    const void* W1 = d_in[2];
    const void* b1 = d_in[3];
    const void* W2 = d_in[4];
    const void* b2 = d_in[5];

    int N = in_sizes[0] / 256;          // 50000
    int E = in_sizes[1] / 2;            // 1600000
    int NB = (N + BSZ - 1) / BSZ;       // 391 buckets of 128 nodes

    char* p = (char*)d_ws;
    auto alloc = [&](size_t bytes) {
        char* r = p;
        p += (bytes + 255) & ~(size_t)255;
        return r;
    };
    int*            flags  = (int*)alloc(8);
    int*            boff   = (int*)alloc(516 * 4);
    int*            offs   = (int*)alloc(((size_t)N + 1) * 4);
    float*          dinv   = (float*)alloc((size_t)N * 4);
    unsigned short* wt1    = (unsigned short*)alloc(256 * 256 * 2);
    unsigned short* wt2    = (unsigned short*)alloc(256 * 256 * 2);
    int*            csr    = (int*)alloc((size_t)E * 4);
    unsigned short* buf0   = (unsigned short*)alloc((size_t)N * 256 * 2);
    unsigned short* buf1   = (unsigned short*)alloc((size_t)N * 256 * 2);
    unsigned*       tmp    = (unsigned*)buf1;   // dead until first gemm; E*4 <= N*512
    int*            cmat   = (int*)buf0;        // dead until k_cvt8;  NB*NBLK*4 = 400 KB

    int nF = N * 256;

    k_flags<<<1, 64, 0, stream>>>((const unsigned*)x, ei, E, flags);
    k_cmat<<<NBLK, 256, 0, stream>>>(ei, E, flags, cmat, NB);
    k_cscan<<<1, 512, 0, stream>>>(cmat, boff, offs, NB, N, E);
    k_fillmat<<<NBLK, 256, 0, stream>>>(ei, E, flags, cmat, tmp, NB);
    k_bbuild<<<NB, 256, 0, stream>>>(tmp, boff, offs, dinv, csr, N);

    k_cvt8<<<(nF / 8 + 255) / 256, 256, 0, stream>>>(x, buf0, nF / 8, flags);
    k_cvtT<<<256, 256, 0, stream>>>(W1, wt1, flags);
    k_cvtT<<<256, 256, 0, stream>>>(W2, wt2, flags);

    int gAgg = (N + 3) / 4;
    k_gemm<<<(N + 63) / 64, 256, 0, stream>>>(buf0, wt1, buf1, N);           // XW1
    k_agg<<<gAgg, 256, 0, stream>>>(buf1, csr, offs, dinv, b1,
                                    (void*)buf0, 1, 0, flags, N);            // h (bf16)
    k_gemm<<<(N + 63) / 64, 256, 0, stream>>>(buf0, wt2, buf1, N);           // HW2
    k_agg<<<gAgg, 256, 0, stream>>>(buf1, csr, offs, dinv, b2,
                                    d_out, 0, 1, flags, N);                  // final
}